// Round 13
// baseline (110.412 us; speedup 1.0000x reference)
//
#include <hip/hip_runtime.h>
#include <hip/hip_bf16.h>

#define N_ATOMS 512
#define CDIM 64
#define NSIG 16384
#define KS 4
#define NBINS 33
#define NS_BLK 8    // signals per fused block (8 waves; wave = 64 atoms in GEMM, 1 signal in OMP)

// ws layout (floats): [0,32768) Dn[c][n] ; [32768,65536) DnT[n][c] ;
// [65536,327680) G[n][n]
#define WS_DN   0
#define WS_DNT  32768
#define WS_G    65536
#define LOSS_IDX (NSIG * CDIM)

// k_normalize v2: 128 blocks x 256 thr, one column per WAVE (was 1-wave
// blocks: half of each CU's issue width idle + launch tail). The 64-lane
// butterfly + division is wave-local and unchanged -> Dn/DnT bit-identical.
// Also zero-inits the loss slot for the fused kernel's atomics.
__global__ void k_normalize(const float* __restrict__ dict,
                            float* __restrict__ Dn, float* __restrict__ DnT,
                            float* __restrict__ out) {
    const int t = threadIdx.x;
    const int c = t & 63;                    // channel/row (lane)
    const int n = blockIdx.x * 4 + (t >> 6); // atom/column (one per wave)
    float v = dict[c * N_ATOMS + n];
    float sq = v * v;
    #pragma unroll
    for (int off = 32; off > 0; off >>= 1) sq += __shfl_down(sq, off);
    sq = __shfl(sq, 0);
    float m = fmaxf(sqrtf(sq), 1e-10f);
    float r = v / m;             // division to match reference exactly
    Dn[c * N_ATOMS + n] = r;
    DnT[n * CDIM + c]  = r;
    if (n == 0 && c == 0) out[LOSS_IDX] = 0.f;
}

// k_gram v2: 256 blocks x 512 thr, TWO rows per block (256 threads each,
// j strided by 256 — the r0-verified per-row pattern). Per-(i,j) fmaf chain
// over sc unchanged -> G bit-identical. Fewer, fatter blocks = less launch
// tail on a ~3 us kernel. Fused kernel below is r12's verified bytes.
__global__ void k_gram(const float* __restrict__ Dn, float* __restrict__ G) {
    __shared__ float sc[2][CDIM];
    const int t = threadIdx.x;
    const int g = t >> 8;                    // 0..1: which row of the pair
    const int tj = t & 255;
    const int i = blockIdx.x * 2 + g;
    if (tj < CDIM) sc[g][tj] = Dn[tj * N_ATOMS + i];
    __syncthreads();
    for (int j = tj; j < N_ATOMS; j += 256) {
        float a = 0.f;
        #pragma unroll
        for (int c = 0; c < CDIM; c++) a = fmaf(sc[g][c], Dn[c * N_ATOMS + j], a);
        G[i * N_ATOMS + j] = a;
    }
}

// 8-way select, VALUE-passed (pointer-escape of register arrays sends them
// to scratch — round-4 lesson). e wave-uniform; 7-cndmask tree.
__device__ __forceinline__ float sel8v(float f0, float f1, float f2, float f3,
                                       float f4, float f5, float f6, float f7,
                                       int e) {
    float x0 = (e & 1) ? f1 : f0;
    float x1 = (e & 1) ? f3 : f2;
    float x2 = (e & 1) ? f5 : f4;
    float x3 = (e & 1) ? f7 : f6;
    float y0 = (e & 2) ? x1 : x0;
    float y1 = (e & 2) ? x3 : x2;
    return (e & 4) ? y1 : y0;
}
#define SEL8(arr, e) sel8v(arr[0], arr[1], arr[2], arr[3], \
                           arr[4], arr[5], arr[6], arr[7], e)

// DPP max step: v = max(v, v shifted by ctrl). bound_ctrl=1 -> OOB lanes
// contribute +0.0f, safe because all reduced values are >= 0. Pure VALU
// (~4 cy) vs ds_bpermute (~40-120 cy) per level.
#define DPPMAX(v, ctrl)                                                     \
    v = fmaxf(v, __int_as_float(__builtin_amdgcn_update_dpp(                \
            0, __float_as_int(v), (ctrl), 0xf, 0xf, true)))

// readlane broadcast of a float from a wave-uniform lane (replaces
// __shfl with uniform src: v_readlane_b32 instead of ds_bpermute).
__device__ __forceinline__ float rdlane_f(float v, int lane) {
    return __int_as_float(__builtin_amdgcn_readlane(__float_as_int(v), lane));
}

// OMP body v11 — r7/r12's verified bytes (36 VGPR / zero spill / 44.1 us):
// sequential-scan lane argmax (r11's tree+unroll variant regressed 25%),
// DPP row_shr/row_bcast wave max (exact fmaxf), ballot+ffs lowest-lane
// winner (= lowest atom index tie-break), register-kept G rows, readlane
// extractions. Tokens/zste bit-identical to all passing rounds.
__device__ __forceinline__ void omp_body(
    const float hb[8], const float* __restrict__ G, int lane,
    int I[KS], float coef[KS])
{
    float h[8];
    #pragma unroll
    for (int j = 0; j < 8; j++) h[j] = hb[j];

    unsigned sel = 0;
    float L[KS][KS];
    float hsel[KS];
    float inv[KS];
    float r[KS - 1][8];                 // kept G-row fragments (registers)
    L[0][0] = 1.f; inv[0] = 1.f;

    #pragma unroll
    for (int k = 0; k < KS; k++) {
        // lane-local argmax of |where(selected, 0, h)|, lowest-j tie-break
        float bv = -1.f; int bn = N_ATOMS;
        #pragma unroll
        for (int j = 0; j < 8; j++) {
            float v = (sel & (1u << j)) ? 0.f : fabsf(h[j]);
            if (v > bv) { bv = v; bn = lane * 8 + j; }
        }
        // wave max in lane 63 via DPP (VALU-speed), then SGPR broadcast
        float wv = bv;
        DPPMAX(wv, 0x111);   // row_shr:1
        DPPMAX(wv, 0x112);   // row_shr:2
        DPPMAX(wv, 0x114);   // row_shr:4
        DPPMAX(wv, 0x118);   // row_shr:8
        DPPMAX(wv, 0x142);   // row_bcast:15
        DPPMAX(wv, 0x143);   // row_bcast:31
        const float wm = rdlane_f(wv, 63);
        const int win = (int)__ffsll(__ballot(bv == wm)) - 1; // lowest lane
        const int idx = __builtin_amdgcn_readlane(bn, win);
        if ((idx >> 3) == lane) sel |= 1u << (idx & 7);
        const int owner = idx >> 3, e = idx & 7;

        if (k < KS - 1) {   // load row I[k]=idx early; latency hides under solves
            const float4* gr = (const float4*)(G + idx * N_ATOMS + lane * 8);
            float4 g0 = gr[0], g1 = gr[1];
            r[k][0] = g0.x; r[k][1] = g0.y; r[k][2] = g0.z; r[k][3] = g0.w;
            r[k][4] = g1.x; r[k][5] = g1.y; r[k][6] = g1.z; r[k][7] = g1.w;
        }

        if (k > 0) {
            float w[KS - 1];
            #pragma unroll
            for (int i2 = 0; i2 < k; i2++) {
                float t = rdlane_f(SEL8(r[i2], e), owner);  // G[I[i2]][idx]
                #pragma unroll
                for (int j2 = 0; j2 < i2; j2++) t -= L[i2][j2] * w[j2];
                w[i2] = t * inv[i2];
            }
            float ssum = 0.f;
            #pragma unroll
            for (int j2 = 0; j2 < k; j2++) ssum += w[j2] * w[j2];
            float corner = sqrtf(fmaxf(1.f - ssum, 1e-12f));
            #pragma unroll
            for (int j2 = 0; j2 < k; j2++) L[k][j2] = w[j2];
            L[k][k] = corner;
            inv[k] = 1.f / corner;
        }
        I[k] = idx;
        hsel[k] = rdlane_f(SEL8(hb, e), owner);   // hbar[idx], same bits

        float y[KS];
        #pragma unroll
        for (int i2 = 0; i2 <= k; i2++) {
            float t = hsel[i2];
            #pragma unroll
            for (int j2 = 0; j2 < i2; j2++) t -= L[i2][j2] * y[j2];
            y[i2] = t * inv[i2];
        }
        #pragma unroll
        for (int i2 = k; i2 >= 0; i2--) {
            float t = y[i2];
            #pragma unroll
            for (int j2 = i2 + 1; j2 <= k; j2++) t -= L[j2][i2] * coef[j2];
            coef[i2] = t * inv[i2];
        }

        if (k < KS - 1) {
            float a[8];
            #pragma unroll
            for (int j = 0; j < 8; j++) a[j] = 0.f;
            #pragma unroll
            for (int m = 0; m <= k; m++) {
                float cm = coef[m];
                #pragma unroll
                for (int j = 0; j < 8; j++) a[j] = fmaf(cm, r[m][j], a[j]);
            }
            #pragma unroll
            for (int j = 0; j < 8; j++) h[j] = hb[j] - a[j];
        }
    }
}

// Fused v11 (r12 verbatim, byte-frozen): 512 thr, (512,3), 1 signal/wave,
// scalar coalesced Dn GEMM. The only shape that codegens clean (36 VGPR,
// zero spill) at the session-best 44.1 us. All r9-r11 deviations regressed.
__global__ __launch_bounds__(512, 3) void k_fused8(
    const float* __restrict__ z, const float* __restrict__ Dn,
    const float* __restrict__ DnT, const float* __restrict__ G,
    float* __restrict__ out)
{
    __shared__ float Xs[CDIM][NS_BLK];      // [c][s] 2 KB
    __shared__ float Hs[NS_BLK][516];       // hbar tile 16.5 KB; reused for zste
    __shared__ float tk[NS_BLK][4];
    __shared__ float lred[NS_BLK];
    const int t = threadIdx.x;
    const int wave = t >> 6, lane = t & 63;
    const int s0 = blockIdx.x * NS_BLK;
    const int b = s0 >> 10;
    const int hw0 = s0 & 1023;

    if (t < 128) {   // coalesced z stage: c = t>>1, signals f..f+3 (f = (t&1)*4)
        const int c = t >> 1, f = (t & 1) * 4;
        float4 v = *(const float4*)(z + (b * CDIM + c) * 1024 + hw0 + f);
        Xs[c][f + 0] = v.x; Xs[c][f + 1] = v.y;
        Xs[c][f + 2] = v.z; Xs[c][f + 3] = v.w;
    }
    __syncthreads();

    {   // GEMM: wave owns atoms [wave*64, +64); lane owns 1 atom.
        // k-ascending fmaf per (signal, atom) — bit-identical to prior rounds.
        const int n0 = wave * 64 + lane;
        float acc[NS_BLK];
        #pragma unroll
        for (int q = 0; q < NS_BLK; q++) acc[q] = 0.f;
        for (int k = 0; k < CDIM; k++) {
            const float d = Dn[k * N_ATOMS + n0];
            float4 xlo = *(const float4*)(&Xs[k][0]);
            float4 xhi = *(const float4*)(&Xs[k][4]);
            const float xs[NS_BLK] = {xlo.x, xlo.y, xlo.z, xlo.w,
                                      xhi.x, xhi.y, xhi.z, xhi.w};
            #pragma unroll
            for (int q = 0; q < NS_BLK; q++)
                acc[q] = fmaf(xs[q], d, acc[q]);
        }
        #pragma unroll
        for (int q = 0; q < NS_BLK; q++) Hs[q][n0] = acc[q];
    }
    __syncthreads();

    // OMP: one signal per wave (sl = wave). 8 independent chains per block.
    {
        const int sl = wave;
        const float xch = Xs[lane][sl];

        float hb[8];
        *(float4*)(&hb[0]) = *(const float4*)(&Hs[sl][lane * 8]);
        *(float4*)(&hb[4]) = *(const float4*)(&Hs[sl][lane * 8 + 4]);

        int I[KS]; float coef[KS];
        omp_body(hb, G, lane, I, coef);

        int tok[KS]; float cq[KS];
        #pragma unroll
        for (int j = 0; j < KS; j++) {
            float c2 = fminf(fmaxf(coef[j], -2.f), 2.f);
            float bf = (c2 + 2.f) / 4.f * 32.f;
            int bin = (int)rintf(bf);
            bin = bin < 0 ? 0 : (bin > 32 ? 32 : bin);
            cq[j] = -2.f + 0.125f * (float)bin;
            tok[j] = I[j] * NBINS + bin;
        }
        float zq = 0.f;
        #pragma unroll
        for (int j = 0; j < KS; j++)
            zq = fmaf(cq[j], DnT[I[j] * CDIM + lane], zq);

        float diff = zq - xch;
        Hs[sl][lane] = xch + (zq - xch);   // zste overlay (row sl read is done)

        float sq = diff * diff;
        #pragma unroll
        for (int off = 32; off > 0; off >>= 1) sq += __shfl_down(sq, off);
        if (lane == 0) lred[sl] = sq;
        if (lane < KS) tk[sl][lane] = (float)tok[lane];
    }
    __syncthreads();

    if (t < 128) {   // coalesced zste write: c = t>>1, signals f..f+3
        const int c = t >> 1, f = (t & 1) * 4;
        float4 v;
        v.x = Hs[f + 0][c]; v.y = Hs[f + 1][c];
        v.z = Hs[f + 2][c]; v.w = Hs[f + 3][c];
        *(float4*)(out + (b * CDIM + c) * 1024 + hw0 + f) = v;
    }
    if (t < NS_BLK * KS)   // 32 consecutive token floats
        out[NSIG * CDIM + 1 + s0 * KS + t] = tk[t >> 2][t & 3];
    if (t == 0) {          // one pre-scaled atomic per block; 1.25/2^20 exact
        float bl = 0.f;
        #pragma unroll
        for (int q = 0; q < NS_BLK; q++) bl += lred[q];
        atomicAdd(out + LOSS_IDX, bl * (1.25f / 1048576.f));
    }
}

extern "C" void kernel_launch(void* const* d_in, const int* in_sizes, int n_in,
                              void* d_out, int out_size, void* d_ws, size_t ws_size,
                              hipStream_t stream) {
    const float* z    = (const float*)d_in[0];
    const float* dict = (const float*)d_in[1];
    float* out  = (float*)d_out;
    float* w    = (float*)d_ws;
    float* Dn   = w + WS_DN;
    float* DnT  = w + WS_DNT;
    float* G    = w + WS_G;

    hipLaunchKernelGGL(k_normalize, dim3(N_ATOMS / 4), dim3(256), 0, stream,
                       dict, Dn, DnT, out);
    hipLaunchKernelGGL(k_gram,      dim3(N_ATOMS / 2), dim3(512), 0, stream, Dn, G);
    hipLaunchKernelGGL(k_fused8,    dim3(NSIG / NS_BLK), dim3(512), 0, stream,
                       z, Dn, DnT, G, out);
}

// Round 14
// 101.071 us; speedup vs baseline: 1.0924x; 1.0924x over previous
//
#include <hip/hip_runtime.h>
#include <hip/hip_bf16.h>

#define N_ATOMS 512
#define CDIM 64
#define NSIG 16384
#define KS 4
#define NBINS 33
#define NS_BLK 8    // signals per fused block (8 waves; wave = 64 atoms in GEMM, 1 signal in OMP)

// ws layout (floats): [0,32768) Dn[c][n] ; [32768,65536) DnT[n][c] ;
// [65536,327680) G[n][n]
#define WS_DN   0
#define WS_DNT  32768
#define WS_G    65536
#define LOSS_IDX (NSIG * CDIM)

// k_normalize also zero-inits the loss slot for the fused kernel's atomics.
__global__ void k_normalize(const float* __restrict__ dict,
                            float* __restrict__ Dn, float* __restrict__ DnT,
                            float* __restrict__ out) {
    const int n = blockIdx.x;    // atom/column
    const int c = threadIdx.x;   // channel/row (64 threads = 1 wave)
    float v = dict[c * N_ATOMS + n];
    float sq = v * v;
    #pragma unroll
    for (int off = 32; off > 0; off >>= 1) sq += __shfl_down(sq, off);
    sq = __shfl(sq, 0);
    float m = fmaxf(sqrtf(sq), 1e-10f);
    float r = v / m;             // division to match reference exactly
    Dn[c * N_ATOMS + n] = r;
    DnT[n * CDIM + c]  = r;
    if (n == 0 && c == 0) out[LOSS_IDX] = 0.f;
}

// 512 threads: one j per thread. Per-(i,j) fmaf chain over sc unchanged ->
// G bit-identical. (r12's best-measured prep shape.)
__global__ void k_gram(const float* __restrict__ Dn, float* __restrict__ G) {
    __shared__ float sc[CDIM];
    const int i = blockIdx.x;
    const int t = threadIdx.x;
    if (t < CDIM) sc[t] = Dn[t * N_ATOMS + i];
    __syncthreads();
    for (int j = t; j < N_ATOMS; j += 512) {
        float a = 0.f;
        #pragma unroll
        for (int c = 0; c < CDIM; c++) a = fmaf(sc[c], Dn[c * N_ATOMS + j], a);
        G[i * N_ATOMS + j] = a;
    }
}

// 8-way select, VALUE-passed (pointer-escape of register arrays sends them
// to scratch — round-4 lesson). e wave-uniform; 7-cndmask tree.
__device__ __forceinline__ float sel8v(float f0, float f1, float f2, float f3,
                                       float f4, float f5, float f6, float f7,
                                       int e) {
    float x0 = (e & 1) ? f1 : f0;
    float x1 = (e & 1) ? f3 : f2;
    float x2 = (e & 1) ? f5 : f4;
    float x3 = (e & 1) ? f7 : f6;
    float y0 = (e & 2) ? x1 : x0;
    float y1 = (e & 2) ? x3 : x2;
    return (e & 4) ? y1 : y0;
}
#define SEL8(arr, e) sel8v(arr[0], arr[1], arr[2], arr[3], \
                           arr[4], arr[5], arr[6], arr[7], e)

// DPP max step: v = max(v, v shifted by ctrl). bound_ctrl=1 -> OOB lanes
// contribute +0.0f, safe because all reduced values are >= 0. Pure VALU
// (~4 cy) vs ds_bpermute (~40-120 cy) per level.
#define DPPMAX(v, ctrl)                                                     \
    v = fmaxf(v, __int_as_float(__builtin_amdgcn_update_dpp(                \
            0, __float_as_int(v), (ctrl), 0xf, 0xf, true)))

// readlane broadcast of a float from a wave-uniform lane (replaces
// __shfl with uniform src: v_readlane_b32 instead of ds_bpermute).
__device__ __forceinline__ float rdlane_f(float v, int lane) {
    return __int_as_float(__builtin_amdgcn_readlane(__float_as_int(v), lane));
}

// OMP body v11 — the verified bytes (36 VGPR / zero spill / 44.1 us):
// sequential-scan lane argmax (r11's tree+unroll variant regressed 25%),
// DPP row_shr/row_bcast wave max (exact fmaxf), ballot+ffs lowest-lane
// winner (= lowest atom index tie-break), register-kept G rows, readlane
// extractions. Tokens/zste bit-identical to all passing rounds.
__device__ __forceinline__ void omp_body(
    const float hb[8], const float* __restrict__ G, int lane,
    int I[KS], float coef[KS])
{
    float h[8];
    #pragma unroll
    for (int j = 0; j < 8; j++) h[j] = hb[j];

    unsigned sel = 0;
    float L[KS][KS];
    float hsel[KS];
    float inv[KS];
    float r[KS - 1][8];                 // kept G-row fragments (registers)
    L[0][0] = 1.f; inv[0] = 1.f;

    #pragma unroll
    for (int k = 0; k < KS; k++) {
        // lane-local argmax of |where(selected, 0, h)|, lowest-j tie-break
        float bv = -1.f; int bn = N_ATOMS;
        #pragma unroll
        for (int j = 0; j < 8; j++) {
            float v = (sel & (1u << j)) ? 0.f : fabsf(h[j]);
            if (v > bv) { bv = v; bn = lane * 8 + j; }
        }
        // wave max in lane 63 via DPP (VALU-speed), then SGPR broadcast
        float wv = bv;
        DPPMAX(wv, 0x111);   // row_shr:1
        DPPMAX(wv, 0x112);   // row_shr:2
        DPPMAX(wv, 0x114);   // row_shr:4
        DPPMAX(wv, 0x118);   // row_shr:8
        DPPMAX(wv, 0x142);   // row_bcast:15
        DPPMAX(wv, 0x143);   // row_bcast:31
        const float wm = rdlane_f(wv, 63);
        const int win = (int)__ffsll(__ballot(bv == wm)) - 1; // lowest lane
        const int idx = __builtin_amdgcn_readlane(bn, win);
        if ((idx >> 3) == lane) sel |= 1u << (idx & 7);
        const int owner = idx >> 3, e = idx & 7;

        if (k < KS - 1) {   // load row I[k]=idx early; latency hides under solves
            const float4* gr = (const float4*)(G + idx * N_ATOMS + lane * 8);
            float4 g0 = gr[0], g1 = gr[1];
            r[k][0] = g0.x; r[k][1] = g0.y; r[k][2] = g0.z; r[k][3] = g0.w;
            r[k][4] = g1.x; r[k][5] = g1.y; r[k][6] = g1.z; r[k][7] = g1.w;
        }

        if (k > 0) {
            float w[KS - 1];
            #pragma unroll
            for (int i2 = 0; i2 < k; i2++) {
                float t = rdlane_f(SEL8(r[i2], e), owner);  // G[I[i2]][idx]
                #pragma unroll
                for (int j2 = 0; j2 < i2; j2++) t -= L[i2][j2] * w[j2];
                w[i2] = t * inv[i2];
            }
            float ssum = 0.f;
            #pragma unroll
            for (int j2 = 0; j2 < k; j2++) ssum += w[j2] * w[j2];
            float corner = sqrtf(fmaxf(1.f - ssum, 1e-12f));
            #pragma unroll
            for (int j2 = 0; j2 < k; j2++) L[k][j2] = w[j2];
            L[k][k] = corner;
            inv[k] = 1.f / corner;
        }
        I[k] = idx;
        hsel[k] = rdlane_f(SEL8(hb, e), owner);   // hbar[idx], same bits

        float y[KS];
        #pragma unroll
        for (int i2 = 0; i2 <= k; i2++) {
            float t = hsel[i2];
            #pragma unroll
            for (int j2 = 0; j2 < i2; j2++) t -= L[i2][j2] * y[j2];
            y[i2] = t * inv[i2];
        }
        #pragma unroll
        for (int i2 = k; i2 >= 0; i2--) {
            float t = y[i2];
            #pragma unroll
            for (int j2 = i2 + 1; j2 <= k; j2++) t -= L[j2][i2] * coef[j2];
            coef[i2] = t * inv[i2];
        }

        if (k < KS - 1) {
            float a[8];
            #pragma unroll
            for (int j = 0; j < 8; j++) a[j] = 0.f;
            #pragma unroll
            for (int m = 0; m <= k; m++) {
                float cm = coef[m];
                #pragma unroll
                for (int j = 0; j < 8; j++) a[j] = fmaf(cm, r[m][j], a[j]);
            }
            #pragma unroll
            for (int j = 0; j < 8; j++) h[j] = hb[j] - a[j];
        }
    }
}

// Fused v11 (byte-frozen, best-measured config: 101.2 us total / 44.1 us
// fused): 512 thr, (512,3), 1 signal/wave, scalar coalesced Dn GEMM. The
// only shape that codegens clean (36 VGPR, zero spill). Latency-bound local
// optimum: 6 structural probes (r4/r6/r9/r10/r11) all regressed; occupancy
// 35-60% across rounds showed zero correlation with dur (TLP does not hide
// the serial OMP chain). Remaining stall is the data-dependent
// argmax->G-load->solve recurrence, irreducible in this decomposition.
__global__ __launch_bounds__(512, 3) void k_fused8(
    const float* __restrict__ z, const float* __restrict__ Dn,
    const float* __restrict__ DnT, const float* __restrict__ G,
    float* __restrict__ out)
{
    __shared__ float Xs[CDIM][NS_BLK];      // [c][s] 2 KB
    __shared__ float Hs[NS_BLK][516];       // hbar tile 16.5 KB; reused for zste
    __shared__ float tk[NS_BLK][4];
    __shared__ float lred[NS_BLK];
    const int t = threadIdx.x;
    const int wave = t >> 6, lane = t & 63;
    const int s0 = blockIdx.x * NS_BLK;
    const int b = s0 >> 10;
    const int hw0 = s0 & 1023;

    if (t < 128) {   // coalesced z stage: c = t>>1, signals f..f+3 (f = (t&1)*4)
        const int c = t >> 1, f = (t & 1) * 4;
        float4 v = *(const float4*)(z + (b * CDIM + c) * 1024 + hw0 + f);
        Xs[c][f + 0] = v.x; Xs[c][f + 1] = v.y;
        Xs[c][f + 2] = v.z; Xs[c][f + 3] = v.w;
    }
    __syncthreads();

    {   // GEMM: wave owns atoms [wave*64, +64); lane owns 1 atom.
        // k-ascending fmaf per (signal, atom) — bit-identical to prior rounds.
        const int n0 = wave * 64 + lane;
        float acc[NS_BLK];
        #pragma unroll
        for (int q = 0; q < NS_BLK; q++) acc[q] = 0.f;
        for (int k = 0; k < CDIM; k++) {
            const float d = Dn[k * N_ATOMS + n0];
            float4 xlo = *(const float4*)(&Xs[k][0]);
            float4 xhi = *(const float4*)(&Xs[k][4]);
            const float xs[NS_BLK] = {xlo.x, xlo.y, xlo.z, xlo.w,
                                      xhi.x, xhi.y, xhi.z, xhi.w};
            #pragma unroll
            for (int q = 0; q < NS_BLK; q++)
                acc[q] = fmaf(xs[q], d, acc[q]);
        }
        #pragma unroll
        for (int q = 0; q < NS_BLK; q++) Hs[q][n0] = acc[q];
    }
    __syncthreads();

    // OMP: one signal per wave (sl = wave). 8 independent chains per block.
    {
        const int sl = wave;
        const float xch = Xs[lane][sl];

        float hb[8];
        *(float4*)(&hb[0]) = *(const float4*)(&Hs[sl][lane * 8]);
        *(float4*)(&hb[4]) = *(const float4*)(&Hs[sl][lane * 8 + 4]);

        int I[KS]; float coef[KS];
        omp_body(hb, G, lane, I, coef);

        int tok[KS]; float cq[KS];
        #pragma unroll
        for (int j = 0; j < KS; j++) {
            float c2 = fminf(fmaxf(coef[j], -2.f), 2.f);
            float bf = (c2 + 2.f) / 4.f * 32.f;
            int bin = (int)rintf(bf);
            bin = bin < 0 ? 0 : (bin > 32 ? 32 : bin);
            cq[j] = -2.f + 0.125f * (float)bin;
            tok[j] = I[j] * NBINS + bin;
        }
        float zq = 0.f;
        #pragma unroll
        for (int j = 0; j < KS; j++)
            zq = fmaf(cq[j], DnT[I[j] * CDIM + lane], zq);

        float diff = zq - xch;
        Hs[sl][lane] = xch + (zq - xch);   // zste overlay (row sl read is done)

        float sq = diff * diff;
        #pragma unroll
        for (int off = 32; off > 0; off >>= 1) sq += __shfl_down(sq, off);
        if (lane == 0) lred[sl] = sq;
        if (lane < KS) tk[sl][lane] = (float)tok[lane];
    }
    __syncthreads();

    if (t < 128) {   // coalesced zste write: c = t>>1, signals f..f+3
        const int c = t >> 1, f = (t & 1) * 4;
        float4 v;
        v.x = Hs[f + 0][c]; v.y = Hs[f + 1][c];
        v.z = Hs[f + 2][c]; v.w = Hs[f + 3][c];
        *(float4*)(out + (b * CDIM + c) * 1024 + hw0 + f) = v;
    }
    if (t < NS_BLK * KS)   // 32 consecutive token floats
        out[NSIG * CDIM + 1 + s0 * KS + t] = tk[t >> 2][t & 3];
    if (t == 0) {          // one pre-scaled atomic per block; 1.25/2^20 exact
        float bl = 0.f;
        #pragma unroll
        for (int q = 0; q < NS_BLK; q++) bl += lred[q];
        atomicAdd(out + LOSS_IDX, bl * (1.25f / 1048576.f));
    }
}

extern "C" void kernel_launch(void* const* d_in, const int* in_sizes, int n_in,
                              void* d_out, int out_size, void* d_ws, size_t ws_size,
                              hipStream_t stream) {
    const float* z    = (const float*)d_in[0];
    const float* dict = (const float*)d_in[1];
    float* out  = (float*)d_out;
    float* w    = (float*)d_ws;
    float* Dn   = w + WS_DN;
    float* DnT  = w + WS_DNT;
    float* G    = w + WS_G;

    hipLaunchKernelGGL(k_normalize, dim3(N_ATOMS), dim3(CDIM), 0, stream,
                       dict, Dn, DnT, out);
    hipLaunchKernelGGL(k_gram,      dim3(N_ATOMS), dim3(512),  0, stream, Dn, G);
    hipLaunchKernelGGL(k_fused8,    dim3(NSIG / NS_BLK), dim3(512), 0, stream,
                       z, Dn, DnT, G, out);
}